// Round 1
// baseline (595.471 us; speedup 1.0000x reference)
//
#include <hip/hip_runtime.h>
#include <math.h>
#include <float.h>

#define N_VOX 32768
#define N_CODES 8192
#define DIM 64

// output float offsets (flat, in return order)
#define Q_OFF 0
#define VQ_OFF (N_VOX * DIM)      // 2097152
#define CM_OFF (VQ_OFF + 1)
#define IDX_OFF (VQ_OFF + 2)

// workspace float offsets
#define WS_ACC 0
#define WS_ESQ 64
#define WS_ZSQ (WS_ESQ + N_CODES)   // 8256
#define WS_IDX (WS_ZSQ + N_VOX)     // 41024 (ints)

// ---------------------------------------------------------------- k_prep
// e_sq / z_sq row norms; 16 lanes per row (coalesced 256B per row).
__global__ __launch_bounds__(256) void k_prep(const float* __restrict__ z,
                                              const float* __restrict__ e,
                                              float* __restrict__ ws) {
  int gid = blockIdx.x * 256 + threadIdx.x;
  if (gid == 0) ws[WS_ACC] = 0.f;   // loss accumulator zero (d_ws is poisoned)
  int row = gid >> 4, lane = gid & 15;
  if (row >= N_CODES + N_VOX) return;
  const float* src; float* dst; int r;
  if (row < N_CODES) { r = row; src = e + (size_t)r * DIM; dst = ws + WS_ESQ; }
  else { r = row - N_CODES; src = z + (size_t)r * DIM; dst = ws + WS_ZSQ; }
  float4 a = *(const float4*)(src + lane * 4);
  float s = a.x * a.x + a.y * a.y + a.z * a.z + a.w * a.w;
  #pragma unroll
  for (int off = 8; off; off >>= 1) s += __shfl_xor(s, off, 16);
  if (lane == 0) dst[r] = s;
}

// ---------------------------------------------------------------- k_argmin
// block: 64 voxels x (loop over 64 code tiles of 128)
// threads 256 as (tx=16 codes-dim, ty=16 voxels-dim), per-thread 4v x 8c.
#define BV 64
#define BC 128
#define ZP 68    // zT pitch (pad: transpose writes 2-way max, b128 aligned)
#define EP 132   // eT pitch

__global__ __launch_bounds__(256, 2) void k_argmin(const float* __restrict__ z,
                                                   const float* __restrict__ e,
                                                   float* __restrict__ ws) {
  __shared__ float zT[DIM * ZP];    // 17.0 KB  zT[d][v]
  __shared__ float eT[DIM * EP];    // 33.0 KB  eT[d][c]
  __shared__ float esq_s[BC];
  const int tid = threadIdx.x;
  const int tx = tid & 15, ty = tid >> 4;
  const int vb = blockIdx.x * BV;
  const float* esq_g = ws + WS_ESQ;
  const float* zsq_g = ws + WS_ZSQ;
  int* idx_g = (int*)ws + WS_IDX;

  // stage z tile transposed: zT[d][v]
  for (int i = tid; i < BV * (DIM / 4); i += 256) {       // 1024 float4s
    int v = i >> 4, d4 = (i & 15) << 2;
    float4 a = *(const float4*)(z + (size_t)(vb + v) * DIM + d4);
    zT[(d4 + 0) * ZP + v] = a.x;
    zT[(d4 + 1) * ZP + v] = a.y;
    zT[(d4 + 2) * ZP + v] = a.z;
    zT[(d4 + 3) * ZP + v] = a.w;
  }
  float zsq_r[4];
  #pragma unroll
  for (int i = 0; i < 4; ++i) zsq_r[i] = zsq_g[vb + ty * 4 + i];

  float bval[4]; int bidx[4];
  #pragma unroll
  for (int i = 0; i < 4; ++i) { bval[i] = FLT_MAX; bidx[i] = 0; }

  for (int ct = 0; ct < N_CODES / BC; ++ct) {             // 64 code tiles
    const int cb = ct * BC;
    __syncthreads();                                      // protect eT reuse
    for (int i = tid; i < BC * (DIM / 4); i += 256) {     // 2048 float4s
      int c = i >> 4, d4 = (i & 15) << 2;
      float4 a = *(const float4*)(e + (size_t)(cb + c) * DIM + d4);
      eT[(d4 + 0) * EP + c] = a.x;
      eT[(d4 + 1) * EP + c] = a.y;
      eT[(d4 + 2) * EP + c] = a.z;
      eT[(d4 + 3) * EP + c] = a.w;
    }
    if (tid < BC) esq_s[tid] = esq_g[cb + tid];
    __syncthreads();

    float acc[4][8];
    #pragma unroll
    for (int i = 0; i < 4; ++i)
      #pragma unroll
      for (int j = 0; j < 8; ++j) acc[i][j] = 0.f;

    #pragma unroll 8
    for (int d = 0; d < DIM; ++d) {
      float4 za  = *(const float4*)&zT[d * ZP + ty * 4];
      float4 ea0 = *(const float4*)&eT[d * EP + tx * 8];
      float4 ea1 = *(const float4*)&eT[d * EP + tx * 8 + 4];
      float zr[4] = {za.x, za.y, za.z, za.w};
      float er[8] = {ea0.x, ea0.y, ea0.z, ea0.w, ea1.x, ea1.y, ea1.z, ea1.w};
      #pragma unroll
      for (int i = 0; i < 4; ++i)
        #pragma unroll
        for (int j = 0; j < 8; ++j)
          acc[i][j] = fmaf(zr[i], er[j], acc[i][j]);
    }

    // d2 = (z_sq - 2*dot) + e_sq  (reference's association); ascending c
    #pragma unroll
    for (int j = 0; j < 8; ++j) {
      int c = cb + tx * 8 + j;
      float es = esq_s[tx * 8 + j];
      #pragma unroll
      for (int i = 0; i < 4; ++i) {
        float s = (zsq_r[i] - 2.0f * acc[i][j]) + es;
        if (s < bval[i]) { bval[i] = s; bidx[i] = c; }   // strict <: earliest idx wins
      }
    }
  }

  // cross-thread (over tx) argmin reduction, tie -> smaller index
  __syncthreads();
  float* redV = eT;                       // reuse eT space
  int*   redI = (int*)(eT + BV * 17);
  #pragma unroll
  for (int i = 0; i < 4; ++i) {
    int v = ty * 4 + i;
    redV[v * 17 + tx] = bval[i];
    redI[v * 17 + tx] = bidx[i];
  }
  __syncthreads();
  if (tid < BV) {
    int v = tid;
    float best = redV[v * 17];
    int   bi   = redI[v * 17];
    #pragma unroll
    for (int t = 1; t < 16; ++t) {
      float val = redV[v * 17 + t];
      int   id  = redI[v * 17 + t];
      if (val < best || (val == best && id < bi)) { best = val; bi = id; }
    }
    idx_g[vb + v] = bi;
  }
}

// ---------------------------------------------------------------- k_out
// gather quantized rows, write indices (float), accumulate (z-q)^2
__global__ __launch_bounds__(256) void k_out(const float* __restrict__ z,
                                             const float* __restrict__ e,
                                             float* __restrict__ ws,
                                             float* __restrict__ out) {
  const int tid = threadIdx.x;
  const int l4 = tid & 15;
  const int* idx_g = (const int*)ws + WS_IDX;
  float local = 0.f;
  int group = (blockIdx.x * 256 + tid) >> 4;          // 4096 groups of 16 lanes
  for (int n = group; n < N_VOX; n += 4096) {
    int idx = idx_g[n];
    float4 e4 = *(const float4*)(e + (size_t)idx * DIM + l4 * 4);
    float4 z4 = *(const float4*)(z + (size_t)n * DIM + l4 * 4);
    *(float4*)(out + Q_OFF + (size_t)n * DIM + l4 * 4) = e4;
    float dx = z4.x - e4.x, dy = z4.y - e4.y, dz = z4.z - e4.z, dw = z4.w - e4.w;
    local += dx * dx + dy * dy + dz * dz + dw * dw;
    if (l4 == 0) out[IDX_OFF + n] = (float)idx;
  }
  #pragma unroll
  for (int off = 32; off; off >>= 1) local += __shfl_xor(local, off);
  __shared__ float wsum[4];
  if ((tid & 63) == 0) wsum[tid >> 6] = local;
  __syncthreads();
  if (tid == 0) atomicAdd(ws + WS_ACC, wsum[0] + wsum[1] + wsum[2] + wsum[3]);
}

// ---------------------------------------------------------------- k_fin
__global__ void k_fin(const float* __restrict__ ws, float* __restrict__ out) {
  float m = ws[WS_ACC] * (1.0f / (float)(N_VOX * DIM));
  out[VQ_OFF] = m;   // vq_loss
  out[CM_OFF] = m;   // commitment_loss (identical forward value)
}

// ----------------------------------------------------------------
extern "C" void kernel_launch(void* const* d_in, const int* in_sizes, int n_in,
                              void* d_out, int out_size, void* d_ws, size_t ws_size,
                              hipStream_t stream) {
  const float* z = (const float*)d_in[0];
  const float* e = (const float*)d_in[1];
  float* out = (float*)d_out;
  float* ws = (float*)d_ws;

  k_prep<<<(16 * (N_CODES + N_VOX)) / 256, 256, 0, stream>>>(z, e, ws);
  k_argmin<<<N_VOX / BV, 256, 0, stream>>>(z, e, ws);
  k_out<<<256, 256, 0, stream>>>(z, e, ws, out);
  k_fin<<<1, 1, 0, stream>>>(ws, out);
}

// Round 2
// 194.437 us; speedup vs baseline: 3.0625x; 3.0625x over previous
//
#include <hip/hip_runtime.h>
#include <float.h>

#define N_VOX 32768
#define N_CODES 8192
#define DIM 64

// output float offsets (flat, in return order)
#define Q_OFF 0
#define VQ_OFF (N_VOX * DIM)      // 2097152
#define CM_OFF (VQ_OFF + 1)
#define IDX_OFF (VQ_OFF + 2)

// workspace float offsets
#define WS_ACC 0
#define WS_ESQH 64                    // 8192 floats: ||e||^2 / 2
#define WS_IDX (WS_ESQH + N_CODES)    // 8256: 32768 ints
#define WS_EHI (WS_IDX + N_VOX)       // 41024: codebook hi-plane f16 (1 MB)
#define WS_ELO (WS_EHI + N_CODES * DIM / 2)  // 303168: lo-plane f16 (1 MB)
// total ws: (303168 + 262144) * 4 B = 2,261,248 bytes

typedef _Float16 half8 __attribute__((ext_vector_type(8)));
typedef float floatx4 __attribute__((ext_vector_type(4)));

// async global->LDS, 16 B per lane; lds dest must be wave-uniform base (+lane*16)
__device__ inline void gld16(const void* g, void* l) {
  __builtin_amdgcn_global_load_lds(
      (const __attribute__((address_space(1))) unsigned int*)g,
      (__attribute__((address_space(3))) unsigned int*)l, 16, 0, 0);
}
__device__ inline void gld4(const void* g, void* l) {
  __builtin_amdgcn_global_load_lds(
      (const __attribute__((address_space(1))) unsigned int*)g,
      (__attribute__((address_space(3))) unsigned int*)l, 4, 0, 0);
}

// ---------------------------------------------------------------- k_cvt
// Pre-convert codebook to hi/lo f16 planes (XOR-swizzled 16B chunks) + esq/2.
// thread = (row, chunk): 8192 rows x 8 chunks of 8 dims.
__global__ __launch_bounds__(256) void k_cvt(const float* __restrict__ e,
                                             float* __restrict__ ws) {
  int gid = blockIdx.x * 256 + threadIdx.x;
  if (gid == 0) ws[WS_ACC] = 0.f;           // loss accumulator (ws is poisoned)
  int row = gid >> 3, c = gid & 7;
  const float* src = e + (size_t)row * DIM + c * 8;
  float4 a = *(const float4*)src;
  float4 b = *(const float4*)(src + 4);
  float x[8] = {a.x, a.y, a.z, a.w, b.x, b.y, b.z, b.w};
  float s = 0.f;
  half8 hv, lv;
  #pragma unroll
  for (int j = 0; j < 8; ++j) {
    s += x[j] * x[j];                       // esq in full fp32 from originals
    _Float16 h = (_Float16)x[j];
    hv[j] = h;
    lv[j] = (_Float16)(x[j] - (float)h);
  }
  s += __shfl_xor(s, 1); s += __shfl_xor(s, 2); s += __shfl_xor(s, 4);
  if (c == 0) ws[WS_ESQH + row] = 0.5f * s;
  int p = (c + row) & 7;                    // XOR/rotate swizzle within row
  ((half8*)(ws + WS_EHI))[row * 8 + p] = hv;
  ((half8*)(ws + WS_ELO))[row * 8 + p] = lv;
}

// ---------------------------------------------------------------- k_argmin
// Block: 64 voxels, 4 waves = 2 voxel-groups(32) x 2 code-halves.
// Wave: 32 voxels (2 m-frags) x 64 codes per 128-code tile, 64 tiles.
// Distance surrogate per (voxel, code): t = esq/2 - dot (z_sq constant drops).
// dot via 4-term f16 split MFMA: hh + hl + lh + ll (error ~ fp32 level).
__global__ __launch_bounds__(256, 2) void k_argmin(const float* __restrict__ z,
                                                   float* __restrict__ ws) {
  __shared__ __align__(16) _Float16 sBhi[128 * 64];   // 16 KB
  __shared__ __align__(16) _Float16 sBlo[128 * 64];   // 16 KB
  __shared__ float sEsq[128];
  __shared__ float sMval[128];
  __shared__ int   sMidx[128];

  const int tid  = threadIdx.x;
  const int lane = tid & 63;
  const int wave = tid >> 6;
  const int n16  = lane & 15;
  const int quad = lane >> 4;
  const int vgrp = wave >> 1;     // which 32-voxel group
  const int chalf = wave & 1;     // which 64-code half of the tile
  const int vb = blockIdx.x * 64;

  const char* ehi_b = (const char*)(ws + WS_EHI);
  const char* elo_b = (const char*)(ws + WS_ELO);
  const char* esq_b = (const char*)(ws + WS_ESQH);

  // A fragments: 32 voxels x 64 dims, hi/lo. A[m=lane&15][k=quad*8+j (+32*kc)]
  half8 ahi[2][2], alo[2][2];
  #pragma unroll
  for (int m = 0; m < 2; ++m)
    #pragma unroll
    for (int kc = 0; kc < 2; ++kc) {
      const float* src = z + (size_t)(vb + vgrp * 32 + m * 16 + n16) * DIM
                       + kc * 32 + quad * 8;
      float4 a = *(const float4*)src;
      float4 b = *(const float4*)(src + 4);
      float x[8] = {a.x, a.y, a.z, a.w, b.x, b.y, b.z, b.w};
      #pragma unroll
      for (int j = 0; j < 8; ++j) {
        _Float16 h = (_Float16)x[j];
        ahi[m][kc][j] = h;
        alo[m][kc][j] = (_Float16)(x[j] - (float)h);
      }
    }

  float bval[2][4]; int bidx[2][4];
  #pragma unroll
  for (int m = 0; m < 2; ++m)
    #pragma unroll
    for (int r = 0; r < 4; ++r) { bval[m][r] = FLT_MAX; bidx[m][r] = 0; }

  // swizzled chunk offsets (f16 units) for this lane's B-row reads
  const int s0 = ((quad + n16) & 7) * 8;          // kc=0 chunk
  const int s1 = ((quad + 4 + n16) & 7) * 8;      // kc=1 chunk

  for (int ct = 0; ct < 64; ++ct) {
    const int cb = ct * 128;
    __syncthreads();                              // protect LDS reuse
    // stage 128 codes: hi+lo planes (32 KB) via async global->LDS
    #pragma unroll
    for (int r = 0; r < 4; ++r) {
      int off = (r * 4 + wave) * 1024;            // wave-uniform
      gld16(ehi_b + (size_t)cb * 128 + off + lane * 16, (char*)sBhi + off);
      gld16(elo_b + (size_t)cb * 128 + off + lane * 16, (char*)sBlo + off);
    }
    if (wave == 0) {
      gld4(esq_b + (size_t)cb * 4 + lane * 4, (char*)sEsq);
      gld4(esq_b + (size_t)cb * 4 + 256 + lane * 4, (char*)sEsq + 256);
    }
    __syncthreads();

    #pragma unroll
    for (int t = 0; t < 4; ++t) {
      const int rowb = chalf * 64 + t * 16;
      const int row = rowb + n16;
      half8 bh0 = *(const half8*)&sBhi[row * 64 + s0];
      half8 bh1 = *(const half8*)&sBhi[row * 64 + s1];
      half8 bl0 = *(const half8*)&sBlo[row * 64 + s0];
      half8 bl1 = *(const half8*)&sBlo[row * 64 + s1];
      float eh = sEsq[row];
      int code = cb + row;
      #pragma unroll
      for (int m = 0; m < 2; ++m) {
        floatx4 acc = {0.f, 0.f, 0.f, 0.f};
        acc = __builtin_amdgcn_mfma_f32_16x16x32_f16(ahi[m][0], bh0, acc, 0, 0, 0);
        acc = __builtin_amdgcn_mfma_f32_16x16x32_f16(ahi[m][1], bh1, acc, 0, 0, 0);
        acc = __builtin_amdgcn_mfma_f32_16x16x32_f16(ahi[m][0], bl0, acc, 0, 0, 0);
        acc = __builtin_amdgcn_mfma_f32_16x16x32_f16(ahi[m][1], bl1, acc, 0, 0, 0);
        acc = __builtin_amdgcn_mfma_f32_16x16x32_f16(alo[m][0], bh0, acc, 0, 0, 0);
        acc = __builtin_amdgcn_mfma_f32_16x16x32_f16(alo[m][1], bh1, acc, 0, 0, 0);
        acc = __builtin_amdgcn_mfma_f32_16x16x32_f16(alo[m][0], bl0, acc, 0, 0, 0);
        acc = __builtin_amdgcn_mfma_f32_16x16x32_f16(alo[m][1], bl1, acc, 0, 0, 0);
        // C layout: col = lane&15 (code = this lane's row), row m_c = quad*4+r
        #pragma unroll
        for (int r = 0; r < 4; ++r) {
          float tv = eh - acc[r];
          if (tv < bval[m][r]) { bval[m][r] = tv; bidx[m][r] = code; }
        }
      }
    }
  }

  // reduce across the 16 lanes (n16) holding each voxel's partials
  #pragma unroll
  for (int m = 0; m < 2; ++m)
    #pragma unroll
    for (int r = 0; r < 4; ++r) {
      float v = bval[m][r]; int i = bidx[m][r];
      #pragma unroll
      for (int off = 1; off < 16; off <<= 1) {
        float ov = __shfl_xor(v, off);
        int   oi = __shfl_xor(i, off);
        if (ov < v || (ov == v && oi < i)) { v = ov; i = oi; }
      }
      if (n16 == 0) {
        int vox = vgrp * 32 + m * 16 + quad * 4 + r;
        sMval[chalf * 64 + vox] = v;
        sMidx[chalf * 64 + vox] = i;
      }
    }
  __syncthreads();
  if (tid < 64) {
    float v0 = sMval[tid], v1 = sMval[64 + tid];
    int   i0 = sMidx[tid], i1 = sMidx[64 + tid];
    bool p1 = (v1 < v0) || (v1 == v0 && i1 < i0);
    ((int*)ws)[WS_IDX + vb + tid] = p1 ? i1 : i0;
  }
}

// ---------------------------------------------------------------- k_out
// gather quantized rows, write indices (float), accumulate (z-q)^2
__global__ __launch_bounds__(256) void k_out(const float* __restrict__ z,
                                             const float* __restrict__ e,
                                             float* __restrict__ ws,
                                             float* __restrict__ out) {
  const int tid = threadIdx.x;
  const int l4 = tid & 15;
  const int* idx_g = (const int*)ws + WS_IDX;
  float local = 0.f;
  int group = (blockIdx.x * 256 + tid) >> 4;          // 4096 groups of 16 lanes
  for (int n = group; n < N_VOX; n += 4096) {
    int idx = idx_g[n];
    float4 e4 = *(const float4*)(e + (size_t)idx * DIM + l4 * 4);
    float4 z4 = *(const float4*)(z + (size_t)n * DIM + l4 * 4);
    *(float4*)(out + Q_OFF + (size_t)n * DIM + l4 * 4) = e4;
    float dx = z4.x - e4.x, dy = z4.y - e4.y, dz = z4.z - e4.z, dw = z4.w - e4.w;
    local += dx * dx + dy * dy + dz * dz + dw * dw;
    if (l4 == 0) out[IDX_OFF + n] = (float)idx;
  }
  #pragma unroll
  for (int off = 32; off; off >>= 1) local += __shfl_xor(local, off);
  __shared__ float wsum[4];
  if ((tid & 63) == 0) wsum[tid >> 6] = local;
  __syncthreads();
  if (tid == 0) atomicAdd(ws + WS_ACC, wsum[0] + wsum[1] + wsum[2] + wsum[3]);
}

// ---------------------------------------------------------------- k_fin
__global__ void k_fin(const float* __restrict__ ws, float* __restrict__ out) {
  float m = ws[WS_ACC] * (1.0f / (float)(N_VOX * DIM));
  out[VQ_OFF] = m;   // vq_loss
  out[CM_OFF] = m;   // commitment_loss (identical forward value)
}

// ----------------------------------------------------------------
extern "C" void kernel_launch(void* const* d_in, const int* in_sizes, int n_in,
                              void* d_out, int out_size, void* d_ws, size_t ws_size,
                              hipStream_t stream) {
  const float* z = (const float*)d_in[0];
  const float* e = (const float*)d_in[1];
  float* out = (float*)d_out;
  float* ws = (float*)d_ws;

  k_cvt<<<(N_CODES * 8) / 256, 256, 0, stream>>>(e, ws);
  k_argmin<<<N_VOX / 64, 256, 0, stream>>>(z, ws);
  k_out<<<256, 256, 0, stream>>>(z, e, ws, out);
  k_fin<<<1, 1, 0, stream>>>(ws, out);
}